// Round 3
// baseline (466.126 us; speedup 1.0000x reference)
//
#include <hip/hip_runtime.h>
#include <hip/hip_cooperative_groups.h>
#include <hip/hip_bf16.h>
#include <math.h>
#include <stdint.h>

namespace cg = cooperative_groups;

// Problem constants
constexpr int BATCH  = 8;
constexpr int SEQ    = 512;
constexpr int HEADS  = 12;
constexpr int HSIZE  = 64;
constexpr int HIDDEN = 768;
constexpr int OUTD   = 1536;           // HEADS * 2 * HSIZE
constexpr int M      = BATCH * SEQ;    // 4096
constexpr int BH     = BATCH * HEADS;  // 96

// Masked-logit value: bf16 max-negative-FINITE (0xFF7F0000). Ref uses fp32 min
// which is -inf in bf16; finite neighbor keeps |ref-act| non-NaN.
#define NEG_INF (-3.3895313892515355e38f)

typedef short  s16x8 __attribute__((ext_vector_type(8)));  // 8 bf16, MFMA A/B frag
typedef float  f32x4 __attribute__((ext_vector_type(4)));  // MFMA C/D frag

__device__ __forceinline__ short f2bf(float f) {
    __hip_bfloat16 h = __float2bfloat16(f);
    return *reinterpret_cast<short*>(&h);
}

// Async global->LDS, 16 B per lane (global_load_lds_dwordx4). LDS dest is
// wave-uniform base + lane*16 (linear); swizzled content is realized by
// pre-swizzling the per-lane GLOBAL source address (m173 pattern).
__device__ __forceinline__ void g2l16(const void* g, void* l) {
    __builtin_amdgcn_global_load_lds(
        reinterpret_cast<const __attribute__((address_space(1))) int*>(
            reinterpret_cast<uintptr_t>(g)),
        reinterpret_cast<__attribute__((address_space(3))) int*>(
            reinterpret_cast<uintptr_t>(l)),
        16, 0, 0);
}

// ---------------------------------------------------------------------------
// Fused persistent cooperative kernel. Grid = 768 blocks x 256 threads =
// exactly 3 blocks/CU (LDS 48 KB union => co-residency holds; launch_bounds
// pins VGPR so occupancy can't drop below 3/CU -- cooperative launch needs
// all 768 resident).
//   Phase 1 (prep):  2752 virtual blocks striped 4-deep per real block.
//   Phase 2 (proj):  1:1, r1's best-measured 2-phase dbuf loop verbatim.
//   Phase 3 (qk):    1536 tiles striped 2-deep per real block.
// grid.sync() (+ __threadfence for cross-XCD L2) at each phase boundary
// replaces two kernel launches and keeps Xb/Wt/Qb/Kb L2-warm.
// ---------------------------------------------------------------------------
__global__ __launch_bounds__(256, 3) void fused_kernel(
    const float* __restrict__ X,      short* __restrict__ Xb,
    const float* __restrict__ W,      short* __restrict__ Wt,
    const float* __restrict__ bias,
    float* __restrict__ sc_sin,       float* __restrict__ sc_cos,
    short* __restrict__ Qb,           short* __restrict__ Kb,
    const int* __restrict__ am,       float* __restrict__ out)
{
    __shared__ __align__(16) union {
        short Ls[32][36];                                             // prep
        union {
            struct { short As[2][128 * 64]; short Bs[2][64 * 64]; } st;  // 48 KB
            float epi[128 * 68];
        } proj;
        struct { short Qs[128 * 64]; short Ks[128 * 64];
                 int amR[128]; int amC[128]; } qk;                    // 33 KB
    } sh;

    const int tid = threadIdx.x;
    const int l   = tid & 63;
    const int w   = tid >> 6;

    // ======================= Phase 1: prep =======================
    for (int vb = blockIdx.x; vb < 2752; vb += 768) {
        __syncthreads();                  // protect Ls reuse across iterations
        if (vb < 1536) {                  // cast X
            const int t = vb * 256 + tid;
            const float4 a = ((const float4*)X)[t * 2];
            const float4 c = ((const float4*)X)[t * 2 + 1];
            s16x8 o;
            o[0] = f2bf(a.x); o[1] = f2bf(a.y); o[2] = f2bf(a.z); o[3] = f2bf(a.w);
            o[4] = f2bf(c.x); o[5] = f2bf(c.y); o[6] = f2bf(c.z); o[7] = f2bf(c.w);
            ((s16x8*)Xb)[t] = o;
        } else if (vb < 2688) {           // transpose W
            const int bid = vb - 1536;
            const int nx = bid % 48, ky = bid / 48;
            const int r  = tid >> 3;
            const int c4 = (tid & 7) * 4;
            const float4 v = *(const float4*)(W + (size_t)(ky * 32 + r) * OUTD + nx * 32 + c4);
            sh.Ls[r][c4 + 0] = f2bf(v.x); sh.Ls[r][c4 + 1] = f2bf(v.y);
            sh.Ls[r][c4 + 2] = f2bf(v.z); sh.Ls[r][c4 + 3] = f2bf(v.w);
            __syncthreads();
            short4 ov;
            ov.x = sh.Ls[c4 + 0][r]; ov.y = sh.Ls[c4 + 1][r];
            ov.z = sh.Ls[c4 + 2][r]; ov.w = sh.Ls[c4 + 3][r];
            *(short4*)(Wt + (size_t)(nx * 32 + r) * HIDDEN + ky * 32 + c4) = ov;
        } else {                          // rope tables [512][32]
            const int t   = (vb - 2688) * 256 + tid;   // 0..16383
            const int pos = t >> 5, pi = t & 31;
            const float invf = exp2f((float)(2 * pi) * (-13.287712379549449f / 64.0f));
            const float ang  = (float)pos * invf;
            sc_sin[t] = sinf(ang);
            sc_cos[t] = cosf(ang);
        }
    }

    __threadfence();
    cg::this_grid().sync();

    // ======================= Phase 2: proj =======================
    // 4096x1536x768 bf16 MFMA 16x16x32, 128x64 tile, BK=64; r1's 2-phase
    // dbuf with global_load_lds staging (best measured variant).
    {
        const int mBase = (blockIdx.x / 24) * 128;
        const int nBase = (blockIdx.x % 24) * 64;
        const int wm = w * 32;

        // Per-lane pre-swizzled global sources. Wave w stages A rows
        // 32w..32w+31 (4 x 1KiB chunks) and B rows 16w..16w+15 (2 chunks).
        const int lr = l >> 3;            // row-within-chunk 0..7
        const int gc = (l & 7) ^ lr;      // source 16B-chunk within the row
        const short* aSrc = Xb + (size_t)(mBase + wm + lr)     * HIDDEN + gc * 8;
        const short* bSrc = Wt + (size_t)(nBase + w * 16 + lr) * HIDDEN + gc * 8;

#define STAGE(buf_, k0_)                                                     \
    do {                                                                     \
        _Pragma("unroll")                                                    \
        for (int p = 0; p < 4; ++p)                                          \
            g2l16(aSrc + (k0_) + p * 8 * HIDDEN,                             \
                  sh.proj.st.As[buf_] + (w * 4 + p) * 512);                  \
        _Pragma("unroll")                                                    \
        for (int p = 0; p < 2; ++p)                                          \
            g2l16(bSrc + (k0_) + p * 8 * HIDDEN,                             \
                  sh.proj.st.Bs[buf_] + (w * 2 + p) * 512);                  \
    } while (0)

        STAGE(0, 0);
        __syncthreads();   // buf0 ready (barrier drains vmcnt)

        f32x4 acc[2][4] = {};
        int buf = 0;

        for (int k0 = 0; k0 < HIDDEN; k0 += 64) {
            if (k0 + 64 < HIDDEN)
                STAGE(buf ^ 1, k0 + 64);   // async into other buffer
            const short* Asb = sh.proj.st.As[buf];
            const short* Bsb = sh.proj.st.Bs[buf];
#pragma unroll
            for (int s = 0; s < 2; ++s) {
                const int c = ((s * 4 + (l >> 4)) ^ (l & 7)) * 8;
                s16x8 af[2], bf[4];
#pragma unroll
                for (int i = 0; i < 2; ++i)
                    af[i] = *(const s16x8*)(Asb + (wm + i * 16 + (l & 15)) * 64 + c);
#pragma unroll
                for (int j = 0; j < 4; ++j)
                    bf[j] = *(const s16x8*)(Bsb + (j * 16 + (l & 15)) * 64 + c);
#pragma unroll
                for (int i = 0; i < 2; ++i)
#pragma unroll
                    for (int j = 0; j < 4; ++j)
                        acc[i][j] = __builtin_amdgcn_mfma_f32_16x16x32_bf16(
                            af[i], bf[j], acc[i][j], 0, 0, 0);
            }
            __syncthreads();  // drains staged loads; LDS reads done
            buf ^= 1;
        }
#undef STAGE

        // Epilogue stage 1: raw fp32 acc -> LDS [row][n] (C/D: col=lane&15,
        // row=quad*4+reg; waves own disjoint 32-row bands -> single pass).
        const int colL = l & 15, quad = l >> 4;
#pragma unroll
        for (int j = 0; j < 4; ++j) {
            const int nl = j * 16 + colL;
#pragma unroll
            for (int i = 0; i < 2; ++i)
#pragma unroll
                for (int r = 0; r < 4; ++r)
                    sh.proj.epi[(wm + i * 16 + quad * 4 + r) * 68 + nl] = acc[i][j][r];
        }
        __syncthreads();

        // Epilogue stage 2: bias + RoPE -> coalesced 16 B stores into one
        // contiguous Q-or-K head region.
        const int bb   = mBase >> 9;
        const int pos0 = mBase & 511;
        const int h    = nBase >> 7;
        const int slot = (nBase >> 6) & 1;
        short* dst = (slot ? Kb : Qb) + ((size_t)(bb * HEADS + h) * SEQ + pos0) * HSIZE;

#pragma unroll
        for (int p = 0; p < 4; ++p) {
            const int c    = tid + p * 256;   // 0..1023
            const int mrow = c >> 3;          // 0..127
            const int ch   = c & 7;           // 8-dim chunk
            const int dloc = ch * 8;
            const int pos  = pos0 + mrow;

            const float* src = &sh.proj.epi[mrow * 68 + dloc];
            const float4 v0 = *(const float4*)(src);
            const float4 v1 = *(const float4*)(src + 4);
            const float* bp = bias + nBase + dloc;
            const float4 b0 = *(const float4*)(bp);
            const float4 b1 = *(const float4*)(bp + 4);
            const float4 sn = *(const float4*)(sc_sin + pos * 32 + (dloc >> 1));
            const float4 cs = *(const float4*)(sc_cos + pos * 32 + (dloc >> 1));

            const float e0 = v0.x + b0.x, o0 = v0.y + b0.y;
            const float e1 = v0.z + b0.z, o1 = v0.w + b0.w;
            const float e2 = v1.x + b1.x, o2 = v1.y + b1.y;
            const float e3 = v1.z + b1.z, o3 = v1.w + b1.w;
            s16x8 ov;
            ov[0] = f2bf(e0 * cs.x - o0 * sn.x); ov[1] = f2bf(e0 * sn.x + o0 * cs.x);
            ov[2] = f2bf(e1 * cs.y - o1 * sn.y); ov[3] = f2bf(e1 * sn.y + o1 * cs.y);
            ov[4] = f2bf(e2 * cs.z - o2 * sn.z); ov[5] = f2bf(e2 * sn.z + o2 * cs.z);
            ov[6] = f2bf(e3 * cs.w - o3 * sn.w); ov[7] = f2bf(e3 * sn.w + o3 * cs.w);
            *(s16x8*)(dst + (size_t)mrow * HSIZE + dloc) = ov;
        }
    }

    __threadfence();
    cg::this_grid().sync();

    // ======================= Phase 3: qk =======================
    // Per (b,h): S = Q K^T / 8 with causal + attention mask. 1536 tiles
    // (4x4x96), 2 per block. Body identical to the measured r1 variant.
    for (int t = blockIdx.x; t < 1536; t += 768) {
        const int n0  = (t & 3) * 128;
        const int m0  = ((t >> 2) & 3) * 128;
        const int bh  = t >> 4;
        const int bb  = bh / HEADS;

        __syncthreads();                  // LDS reuse across tiles/phases

        if (m0 >= n0 + 128) {   // entire tile strictly-lower -> masked fill
            const float4 ninf = make_float4(NEG_INF, NEG_INF, NEG_INF, NEG_INF);
            float* base = out + ((size_t)bh * SEQ + m0) * SEQ + n0;
            const int c = (tid & 31) * 4;
#pragma unroll
            for (int r = 0; r < 16; ++r) {
                const int row = r * 8 + (tid >> 5);
                *(float4*)(base + (size_t)row * SEQ + c) = ninf;
            }
            continue;
        }

        if (tid < 128)      sh.qk.amR[tid]       = am[bb * SEQ + m0 + tid];
        else                sh.qk.amC[tid - 128] = am[bb * SEQ + n0 + (tid - 128)];

        // Wave w stages rows 32w..32w+31 of Q and K (4 x 1KiB chunks each),
        // pre-swizzled source chunk g = (l&7) ^ (l>>3), linear LDS dest.
        const int lr = l >> 3;
        const int gc = (l & 7) ^ lr;
        const short* qSrc = Qb + ((size_t)bh * SEQ + m0 + w * 32 + lr) * HSIZE + gc * 8;
        const short* kSrc = Kb + ((size_t)bh * SEQ + n0 + w * 32 + lr) * HSIZE + gc * 8;
#pragma unroll
        for (int p = 0; p < 4; ++p) {
            g2l16(qSrc + p * 8 * HSIZE, sh.qk.Qs + (w * 4 + p) * 512);
            g2l16(kSrc + p * 8 * HSIZE, sh.qk.Ks + (w * 4 + p) * 512);
        }
        __syncthreads();

        const int wm = (w & 1) * 64;
        const int wn = (w >> 1) * 64;
        f32x4 acc[4][4] = {};
#pragma unroll
        for (int s = 0; s < 2; ++s) {
            const int c = ((s * 4 + (l >> 4)) ^ (l & 7)) * 8;
            s16x8 qf[4], kf[4];
#pragma unroll
            for (int i = 0; i < 4; ++i) {
                qf[i] = *(const s16x8*)(sh.qk.Qs + (wm + i * 16 + (l & 15)) * 64 + c);
                kf[i] = *(const s16x8*)(sh.qk.Ks + (wn + i * 16 + (l & 15)) * 64 + c);
            }
#pragma unroll
            for (int i = 0; i < 4; ++i)
#pragma unroll
                for (int j = 0; j < 4; ++j)
                    acc[i][j] = __builtin_amdgcn_mfma_f32_16x16x32_bf16(
                        qf[i], kf[j], acc[i][j], 0, 0, 0);
        }

        // Direct-store epilogue. Row masks hoisted to registers.
        const int colL = l & 15, quad = l >> 4;
        int rm[4][4];
#pragma unroll
        for (int i = 0; i < 4; ++i)
#pragma unroll
            for (int r = 0; r < 4; ++r)
                rm[i][r] = sh.qk.amR[wm + i * 16 + quad * 4 + r];

#pragma unroll
        for (int j = 0; j < 4; ++j) {
            const int nl = wn + j * 16 + colL;
            const int ng = n0 + nl;
            const int an = sh.qk.amC[nl];
#pragma unroll
            for (int i = 0; i < 4; ++i) {
#pragma unroll
                for (int r = 0; r < 4; ++r) {
                    const int ml = wm + i * 16 + quad * 4 + r;
                    const int mg = m0 + ml;
                    float v = acc[i][j][r] * 0.125f;
                    if (ng < mg || !an || !rm[i][r]) v = NEG_INF;
                    out[((size_t)bh * SEQ + mg) * SEQ + ng] = v;
                }
            }
        }
    }
}

extern "C" void kernel_launch(void* const* d_in, const int* in_sizes, int n_in,
                              void* d_out, int out_size, void* d_ws, size_t ws_size,
                              hipStream_t stream) {
    const float* X    = (const float*)d_in[0];
    const float* W    = (const float*)d_in[1];
    const float* bias = (const float*)d_in[2];
    const int*   am   = (const int*)d_in[3];
    float* out = (float*)d_out;

    // Workspace: Xb 6,291,456 | Wt 2,359,296 | Qb 6,291,456 | Kb 6,291,456 |
    // sc_sin 65,536 | sc_cos 65,536  = 21,364,736 B.
    char* ws = (char*)d_ws;
    short* Xb = (short*)(ws);
    short* Wt = (short*)(ws + 6291456);
    short* Qb = (short*)(ws + 8650752);
    short* Kb = (short*)(ws + 14942208);
    float* sc_sin = (float*)(ws + 21233664);
    float* sc_cos = (float*)(ws + 21299200);

    void* args[] = { (void*)&X, (void*)&Xb, (void*)&W, (void*)&Wt, (void*)&bias,
                     (void*)&sc_sin, (void*)&sc_cos, (void*)&Qb, (void*)&Kb,
                     (void*)&am, (void*)&out };
    hipLaunchCooperativeKernel((const void*)fused_kernel, dim3(768), dim3(256),
                               args, 0, stream);
}

// Round 4
// 140.104 us; speedup vs baseline: 3.3270x; 3.3270x over previous
//
#include <hip/hip_runtime.h>
#include <hip/hip_bf16.h>
#include <math.h>
#include <stdint.h>

// Problem constants
constexpr int BATCH  = 8;
constexpr int SEQ    = 512;
constexpr int HEADS  = 12;
constexpr int HSIZE  = 64;
constexpr int HIDDEN = 768;
constexpr int OUTD   = 1536;           // HEADS * 2 * HSIZE
constexpr int M      = BATCH * SEQ;    // 4096
constexpr int BH     = BATCH * HEADS;  // 96

// Masked-logit value: bf16 max-negative-FINITE (0xFF7F0000). Ref uses fp32 min
// which is -inf in bf16; finite neighbor keeps |ref-act| non-NaN.
#define NEG_INF (-3.3895313892515355e38f)

typedef short  s16x8 __attribute__((ext_vector_type(8)));  // 8 bf16, MFMA A/B frag
typedef float  f32x4 __attribute__((ext_vector_type(4)));  // MFMA C/D frag

__device__ __forceinline__ short f2bf(float f) {
    __hip_bfloat16 h = __float2bfloat16(f);
    return *reinterpret_cast<short*>(&h);
}

// Async global->LDS, 16 B per lane (global_load_lds_dwordx4). LDS dest is
// wave-uniform base + lane*16 (linear); swizzled content is realized by
// pre-swizzling the per-lane GLOBAL source address (m173 pattern).
__device__ __forceinline__ void g2l16(const void* g, void* l) {
    __builtin_amdgcn_global_load_lds(
        reinterpret_cast<const __attribute__((address_space(1))) int*>(
            reinterpret_cast<uintptr_t>(g)),
        reinterpret_cast<__attribute__((address_space(3))) int*>(
            reinterpret_cast<uintptr_t>(l)),
        16, 0, 0);
}

// ---------------------------------------------------------------------------
// Kernel A (fused prep): blocks [0,1536): cast X fp32->bf16;
// [1536,2688): transpose+cast W -> Wt; [2688,2752): RoPE sin/cos tables.
// Streaming, no inter-block reuse -> no XCD swizzle (T1 null on such ops).
// ---------------------------------------------------------------------------
__global__ __launch_bounds__(256) void prep_kernel(
    const float* __restrict__ X,  short* __restrict__ Xb,
    const float* __restrict__ W,  short* __restrict__ Wt,
    float* __restrict__ sc_sin,   float* __restrict__ sc_cos)
{
    __shared__ short Ls[32][36];
    const int b   = blockIdx.x;
    const int tid = threadIdx.x;

    if (b < 1536) {                       // cast X
        const int t = b * 256 + tid;
        const float4 a = ((const float4*)X)[t * 2];
        const float4 c = ((const float4*)X)[t * 2 + 1];
        s16x8 o;
        o[0] = f2bf(a.x); o[1] = f2bf(a.y); o[2] = f2bf(a.z); o[3] = f2bf(a.w);
        o[4] = f2bf(c.x); o[5] = f2bf(c.y); o[6] = f2bf(c.z); o[7] = f2bf(c.w);
        ((s16x8*)Xb)[t] = o;
    } else if (b < 2688) {                // transpose W
        const int bid = b - 1536;
        const int nx = bid % 48, ky = bid / 48;
        const int r  = tid >> 3;
        const int c4 = (tid & 7) * 4;
        const float4 v = *(const float4*)(W + (size_t)(ky * 32 + r) * OUTD + nx * 32 + c4);
        Ls[r][c4 + 0] = f2bf(v.x); Ls[r][c4 + 1] = f2bf(v.y);
        Ls[r][c4 + 2] = f2bf(v.z); Ls[r][c4 + 3] = f2bf(v.w);
        __syncthreads();
        short4 ov;
        ov.x = Ls[c4 + 0][r]; ov.y = Ls[c4 + 1][r];
        ov.z = Ls[c4 + 2][r]; ov.w = Ls[c4 + 3][r];
        *(short4*)(Wt + (size_t)(nx * 32 + r) * HIDDEN + ky * 32 + c4) = ov;
    } else {                              // rope tables [512][32]
        const int t   = (b - 2688) * 256 + tid;   // 0..16383
        const int pos = t >> 5, pi = t & 31;
        const float invf = exp2f((float)(2 * pi) * (-13.287712379549449f / 64.0f));
        const float ang  = (float)pos * invf;
        sc_sin[t] = sinf(ang);
        sc_cos[t] = cosf(ang);
    }
}

// ---------------------------------------------------------------------------
// Kernel B: proj GEMM (4096x1536x768) bf16 MFMA 16x16x32, 128x64 tile, BK=64,
// 768 blocks = 3/CU. r1's best-measured 2-phase dbuf loop with
// global_load_lds staging. NEW: 1-D grid + XCD-contiguous swizzle (T1):
// f = (bid%8)*96 + bid/8 -> each XCD owns 4 contiguous m-panels; its L2
// fetches 768 KB of Xb once + the shared 2.4 MB Wt (fits 4 MB).
// Epilogue: fp32 acc -> LDS -> bias+RoPE from tables -> coalesced 16 B
// stores into one contiguous Q-or-K head region.
// ---------------------------------------------------------------------------
__global__ __launch_bounds__(256) void proj_mfma_kernel(
    const short* __restrict__ Xb,     // [4096][768] bf16
    const short* __restrict__ Wt,     // [1536][768] bf16
    const float* __restrict__ bias,   // [1536] fp32
    const float* __restrict__ sc_sin, // [512][32]
    const float* __restrict__ sc_cos, // [512][32]
    short* __restrict__ Qb,           // [96][512][64] bf16
    short* __restrict__ Kb)           // [96][512][64] bf16
{
    union Sh {
        struct { short As[2][128 * 64]; short Bs[2][64 * 64]; } st;  // 48 KB
        float epi[128 * 68];                                          // 34816 B
    };
    __shared__ Sh sh;

    const int tid = threadIdx.x;
    const int l   = tid & 63;
    const int w   = tid >> 6;

    // XCD-contiguous tile decode (768 % 8 == 0 -> bijective).
    const int f     = (blockIdx.x & 7) * 96 + (blockIdx.x >> 3);
    const int mBase = (f / 24) * 128;
    const int nBase = (f % 24) * 64;
    const int wm = w * 32;

    // Per-lane pre-swizzled global sources. Wave w stages A rows 32w..32w+31
    // (4 x 1KiB chunks) and B rows 16w..16w+15 (2 chunks).
    const int lr = l >> 3;            // row-within-chunk 0..7
    const int gc = (l & 7) ^ lr;      // source 16B-chunk within the row
    const short* aSrc = Xb + (size_t)(mBase + wm + lr)     * HIDDEN + gc * 8;
    const short* bSrc = Wt + (size_t)(nBase + w * 16 + lr) * HIDDEN + gc * 8;

#define STAGE(buf_, k0_)                                                     \
    do {                                                                     \
        _Pragma("unroll")                                                    \
        for (int p = 0; p < 4; ++p)                                          \
            g2l16(aSrc + (k0_) + p * 8 * HIDDEN,                             \
                  sh.st.As[buf_] + (w * 4 + p) * 512);                       \
        _Pragma("unroll")                                                    \
        for (int p = 0; p < 2; ++p)                                          \
            g2l16(bSrc + (k0_) + p * 8 * HIDDEN,                             \
                  sh.st.Bs[buf_] + (w * 2 + p) * 512);                       \
    } while (0)

    STAGE(0, 0);
    __syncthreads();   // buf0 ready (barrier drains vmcnt)

    f32x4 acc[2][4] = {};
    int buf = 0;

    for (int k0 = 0; k0 < HIDDEN; k0 += 64) {
        if (k0 + 64 < HIDDEN)
            STAGE(buf ^ 1, k0 + 64);   // async into other buffer, overlaps MFMAs
        const short* Asb = sh.st.As[buf];
        const short* Bsb = sh.st.Bs[buf];
#pragma unroll
        for (int s = 0; s < 2; ++s) {
            const int c = ((s * 4 + (l >> 4)) ^ (l & 7)) * 8;
            s16x8 af[2], bf[4];
#pragma unroll
            for (int i = 0; i < 2; ++i)
                af[i] = *(const s16x8*)(Asb + (wm + i * 16 + (l & 15)) * 64 + c);
#pragma unroll
            for (int j = 0; j < 4; ++j)
                bf[j] = *(const s16x8*)(Bsb + (j * 16 + (l & 15)) * 64 + c);
#pragma unroll
            for (int i = 0; i < 2; ++i)
#pragma unroll
                for (int j = 0; j < 4; ++j)
                    acc[i][j] = __builtin_amdgcn_mfma_f32_16x16x32_bf16(
                        af[i], bf[j], acc[i][j], 0, 0, 0);
        }
        __syncthreads();  // drains staged loads; LDS reads done before restage
        buf ^= 1;
    }
#undef STAGE

    // Epilogue stage 1: raw fp32 acc -> LDS [row][n] (C/D: col=lane&15,
    // row=quad*4+reg; waves own disjoint 32-row bands -> single pass).
    const int colL = l & 15, quad = l >> 4;
#pragma unroll
    for (int j = 0; j < 4; ++j) {
        const int nl = j * 16 + colL;
#pragma unroll
        for (int i = 0; i < 2; ++i)
#pragma unroll
            for (int r = 0; r < 4; ++r)
                sh.epi[(wm + i * 16 + quad * 4 + r) * 68 + nl] = acc[i][j][r];
    }
    __syncthreads();

    // Epilogue stage 2: this block's 64 n-dims = one Q-or-K head slot;
    // output region contiguous [pos0..pos0+127] x 64 dims.
    const int bb   = mBase >> 9;
    const int pos0 = mBase & 511;
    const int h    = nBase >> 7;
    const int slot = (nBase >> 6) & 1;
    short* dst = (slot ? Kb : Qb) + ((size_t)(bb * HEADS + h) * SEQ + pos0) * HSIZE;

#pragma unroll
    for (int p = 0; p < 4; ++p) {
        const int c    = tid + p * 256;   // 0..1023
        const int mrow = c >> 3;          // 0..127
        const int ch   = c & 7;           // 8-dim chunk
        const int dloc = ch * 8;
        const int pos  = pos0 + mrow;

        const float* src = &sh.epi[mrow * 68 + dloc];
        const float4 v0 = *(const float4*)(src);
        const float4 v1 = *(const float4*)(src + 4);
        const float* bp = bias + nBase + dloc;
        const float4 b0 = *(const float4*)(bp);
        const float4 b1 = *(const float4*)(bp + 4);
        const float4 sn = *(const float4*)(sc_sin + pos * 32 + (dloc >> 1));
        const float4 cs = *(const float4*)(sc_cos + pos * 32 + (dloc >> 1));

        const float e0 = v0.x + b0.x, o0 = v0.y + b0.y;
        const float e1 = v0.z + b0.z, o1 = v0.w + b0.w;
        const float e2 = v1.x + b1.x, o2 = v1.y + b1.y;
        const float e3 = v1.z + b1.z, o3 = v1.w + b1.w;
        s16x8 ov;
        ov[0] = f2bf(e0 * cs.x - o0 * sn.x); ov[1] = f2bf(e0 * sn.x + o0 * cs.x);
        ov[2] = f2bf(e1 * cs.y - o1 * sn.y); ov[3] = f2bf(e1 * sn.y + o1 * cs.y);
        ov[4] = f2bf(e2 * cs.z - o2 * sn.z); ov[5] = f2bf(e2 * sn.z + o2 * cs.z);
        ov[6] = f2bf(e3 * cs.w - o3 * sn.w); ov[7] = f2bf(e3 * sn.w + o3 * cs.w);
        *(s16x8*)(dst + (size_t)mrow * HSIZE + dloc) = ov;
    }
}

// ---------------------------------------------------------------------------
// Kernel C: per (b,h) S = Q K^T / 8 with causal + attention mask.
// 128x128 tile; global_load_lds staging with pre-swizzled source; MFMA
// 16x16x32; direct scalar dword stores from the C-layout. NEW: 1-D grid +
// XCD-contiguous swizzle (T1): t = (bid%8)*192 + bid/8 -> each XCD owns 12
// complete bh groups; a bh's Q+K panels (128 KB) stay resident in one L2.
// ---------------------------------------------------------------------------
__global__ __launch_bounds__(256) void qk_mfma_kernel(
    const short* __restrict__ Qb,  // [96][512][64] bf16
    const short* __restrict__ Kb,  // [96][512][64] bf16
    const int*   __restrict__ am,  // [8][512]
    float* __restrict__ out)       // [96][512][512]
{
    // XCD-contiguous tile decode (1536 % 8 == 0 -> bijective).
    // t = bh*16 + mt*4 + nt.
    const int t   = (blockIdx.x & 7) * 192 + (blockIdx.x >> 3);
    const int n0  = (t & 3) * 128;
    const int m0  = ((t >> 2) & 3) * 128;
    const int bh  = t >> 4;
    const int bb  = bh / HEADS;
    const int tid = threadIdx.x;

    if (m0 >= n0 + 128) {   // entire tile strictly-lower -> masked
        const float4 ninf = make_float4(NEG_INF, NEG_INF, NEG_INF, NEG_INF);
        float* base = out + ((size_t)bh * SEQ + m0) * SEQ + n0;
        const int c = (tid & 31) * 4;
#pragma unroll
        for (int r = 0; r < 16; ++r) {
            const int row = r * 8 + (tid >> 5);
            *(float4*)(base + (size_t)row * SEQ + c) = ninf;
        }
        return;
    }

    __shared__ short Qs[128 * 64];
    __shared__ short Ks[128 * 64];
    __shared__ __align__(16) int amR[128];
    __shared__ __align__(16) int amC[128];

    const int l = tid & 63;
    const int w = tid >> 6;
    if (tid < 128)      amR[tid]       = am[bb * SEQ + m0 + tid];
    else                amC[tid - 128] = am[bb * SEQ + n0 + (tid - 128)];

    // Wave w stages rows 32w..32w+31 of Q and K (4 x 1KiB chunks each),
    // pre-swizzled source chunk g = (l&7) ^ (l>>3), linear LDS dest.
    const int lr = l >> 3;
    const int gc = (l & 7) ^ lr;
    const short* qSrc = Qb + ((size_t)bh * SEQ + m0 + w * 32 + lr) * HSIZE + gc * 8;
    const short* kSrc = Kb + ((size_t)bh * SEQ + n0 + w * 32 + lr) * HSIZE + gc * 8;
#pragma unroll
    for (int p = 0; p < 4; ++p) {
        g2l16(qSrc + p * 8 * HSIZE, Qs + (w * 4 + p) * 512);
        g2l16(kSrc + p * 8 * HSIZE, Ks + (w * 4 + p) * 512);
    }
    __syncthreads();

    const int wm = (w & 1) * 64;
    const int wn = (w >> 1) * 64;
    f32x4 acc[4][4] = {};
#pragma unroll
    for (int s = 0; s < 2; ++s) {
        const int c = ((s * 4 + (l >> 4)) ^ (l & 7)) * 8;
        s16x8 qf[4], kf[4];
#pragma unroll
        for (int i = 0; i < 4; ++i) {
            qf[i] = *(const s16x8*)(Qs + (wm + i * 16 + (l & 15)) * 64 + c);
            kf[i] = *(const s16x8*)(Ks + (wn + i * 16 + (l & 15)) * 64 + c);
        }
#pragma unroll
        for (int i = 0; i < 4; ++i)
#pragma unroll
            for (int j = 0; j < 4; ++j)
                acc[i][j] = __builtin_amdgcn_mfma_f32_16x16x32_bf16(
                    qf[i], kf[j], acc[i][j], 0, 0, 0);
    }

    // Direct-store epilogue. Row masks hoisted to registers.
    const int colL = l & 15, quad = l >> 4;
    int rm[4][4];
#pragma unroll
    for (int i = 0; i < 4; ++i)
#pragma unroll
        for (int r = 0; r < 4; ++r)
            rm[i][r] = amR[wm + i * 16 + quad * 4 + r];

#pragma unroll
    for (int j = 0; j < 4; ++j) {
        const int nl = wn + j * 16 + colL;
        const int ng = n0 + nl;
        const int an = amC[nl];
#pragma unroll
        for (int i = 0; i < 4; ++i) {
#pragma unroll
            for (int r = 0; r < 4; ++r) {
                const int ml = wm + i * 16 + quad * 4 + r;
                const int mg = m0 + ml;
                float v = acc[i][j][r] * 0.125f;
                if (ng < mg || !an || !rm[i][r]) v = NEG_INF;
                out[((size_t)bh * SEQ + mg) * SEQ + ng] = v;
            }
        }
    }
}

extern "C" void kernel_launch(void* const* d_in, const int* in_sizes, int n_in,
                              void* d_out, int out_size, void* d_ws, size_t ws_size,
                              hipStream_t stream) {
    const float* X    = (const float*)d_in[0];
    const float* W    = (const float*)d_in[1];
    const float* bias = (const float*)d_in[2];
    const int*   am   = (const int*)d_in[3];
    float* out = (float*)d_out;

    // Workspace: Xb 6,291,456 | Wt 2,359,296 | Qb 6,291,456 | Kb 6,291,456 |
    // sc_sin 65,536 | sc_cos 65,536  = 21,364,736 B.
    char* ws = (char*)d_ws;
    short* Xb = (short*)(ws);
    short* Wt = (short*)(ws + 6291456);
    short* Qb = (short*)(ws + 8650752);
    short* Kb = (short*)(ws + 14942208);
    float* sc_sin = (float*)(ws + 21233664);
    float* sc_cos = (float*)(ws + 21299200);

    prep_kernel<<<dim3(2752), 256, 0, stream>>>(X, Xb, W, Wt, sc_sin, sc_cos);
    proj_mfma_kernel<<<dim3(768), 256, 0, stream>>>(
        Xb, Wt, bias, sc_sin, sc_cos, Qb, Kb);
    qk_mfma_kernel<<<dim3(1536), 256, 0, stream>>>(Qb, Kb, am, out);
}